// Round 1
// baseline (5997.956 us; speedup 1.0000x reference)
//
#include <hip/hip_runtime.h>
#include <hip/hip_bf16.h>
#include <math.h>

// Problem: B=4, T=2048, C=1024, H=16, D=64, d_half=32
// qkv = x @ w_attn^T   (8192 x 3072)
// rope+rmsnorm on q,k
// causal attention per (b,h)
// out = y @ w_proj^T   (8192 x 1024)

#define TT 2048
#define CC 1024
#define HH 16
#define DD 64

// ---------------------------------------------------------------------------
// Generic C[M,N] = A[M,K] * B[N,K]^T, fp32. BM=BN=128, BK=16, 256 thr, 8x8.
// M,N multiples of 128; K multiple of 16.
// ---------------------------------------------------------------------------
__global__ __launch_bounds__(256) void gemm_abt(const float* __restrict__ A,
                                                const float* __restrict__ B,
                                                float* __restrict__ C,
                                                int M, int N, int K) {
    __shared__ float As[16][128];   // k-major: As[kk][row]
    __shared__ float Bs[16][128];

    const int tid = threadIdx.x;
    const int tx = tid & 15;        // N direction (0..15)
    const int ty = tid >> 4;        // M direction (0..15)
    const int rowC = blockIdx.y * 128;
    const int colC = blockIdx.x * 128;

    // staging: thread loads float4 at (row r0, k kc) and (row r0+64, k kc)
    const int r0 = tid >> 2;            // 0..63
    const int kc = (tid & 3) << 2;      // 0,4,8,12

    const float* Ap = A + (size_t)(rowC + r0) * K + kc;
    const float* Bp = B + (size_t)(colC + r0) * K + kc;
    const size_t rowStep = (size_t)64 * K;

    float acc[8][8];
#pragma unroll
    for (int i = 0; i < 8; ++i)
#pragma unroll
        for (int j = 0; j < 8; ++j) acc[i][j] = 0.f;

    for (int k0 = 0; k0 < K; k0 += 16) {
        float4 a0 = *(const float4*)(Ap + k0);
        float4 a1 = *(const float4*)(Ap + k0 + rowStep);
        float4 b0 = *(const float4*)(Bp + k0);
        float4 b1 = *(const float4*)(Bp + k0 + rowStep);
        __syncthreads();   // previous tile's compute done before overwrite
        As[kc + 0][r0] = a0.x;  As[kc + 1][r0] = a0.y;
        As[kc + 2][r0] = a0.z;  As[kc + 3][r0] = a0.w;
        As[kc + 0][r0 + 64] = a1.x;  As[kc + 1][r0 + 64] = a1.y;
        As[kc + 2][r0 + 64] = a1.z;  As[kc + 3][r0 + 64] = a1.w;
        Bs[kc + 0][r0] = b0.x;  Bs[kc + 1][r0] = b0.y;
        Bs[kc + 2][r0] = b0.z;  Bs[kc + 3][r0] = b0.w;
        Bs[kc + 0][r0 + 64] = b1.x;  Bs[kc + 1][r0 + 64] = b1.y;
        Bs[kc + 2][r0 + 64] = b1.z;  Bs[kc + 3][r0 + 64] = b1.w;
        __syncthreads();
#pragma unroll
        for (int kk = 0; kk < 16; ++kk) {
            float4 av0 = *(const float4*)&As[kk][ty * 8];
            float4 av1 = *(const float4*)&As[kk][ty * 8 + 4];
            float4 bv0 = *(const float4*)&Bs[kk][tx * 8];
            float4 bv1 = *(const float4*)&Bs[kk][tx * 8 + 4];
            float a[8] = {av0.x, av0.y, av0.z, av0.w, av1.x, av1.y, av1.z, av1.w};
            float b[8] = {bv0.x, bv0.y, bv0.z, bv0.w, bv1.x, bv1.y, bv1.z, bv1.w};
#pragma unroll
            for (int i = 0; i < 8; ++i)
#pragma unroll
                for (int j = 0; j < 8; ++j)
                    acc[i][j] += a[i] * b[j];
        }
    }

#pragma unroll
    for (int i = 0; i < 8; ++i) {
        float* Cp = C + (size_t)(rowC + ty * 8 + i) * N + colC + tx * 8;
        float4 w0 = {acc[i][0], acc[i][1], acc[i][2], acc[i][3]};
        float4 w1 = {acc[i][4], acc[i][5], acc[i][6], acc[i][7]};
        ((float4*)Cp)[0] = w0;
        ((float4*)Cp)[1] = w1;
    }
}

// ---------------------------------------------------------------------------
// RoPE + RMSNorm applied in-place to q and k inside qkv (8192 x 3072).
// One wave (64 lanes) per (m, h); lane = d in [0,64).
// ---------------------------------------------------------------------------
__global__ __launch_bounds__(256) void rope_rms(float* __restrict__ qkv,
                                                const float* __restrict__ cosb,
                                                const float* __restrict__ sinb) {
    const int wave = (blockIdx.x * 256 + threadIdx.x) >> 6;   // 0 .. 131071
    const int lane = threadIdx.x & 63;
    const int h = wave & (HH - 1);
    const int m = wave >> 4;                // 0..8191 (b*T + t)
    const int t = m & (TT - 1);
    const int j = lane & 31;
    const float c = cosb[t * 32 + j];
    const float s = sinb[t * 32 + j];
    float* qp = qkv + (size_t)m * (3 * CC) + h * DD;

#pragma unroll
    for (int which = 0; which < 2; ++which) {   // 0 = q, 1 = k
        float* p = qp + which * CC;
        const float x1 = p[j];
        const float x2 = p[j + 32];
        float out = (lane < 32) ? (x1 * c + x2 * s) : (x2 * c - x1 * s);
        float ss = out * out;
#pragma unroll
        for (int off = 32; off > 0; off >>= 1) ss += __shfl_xor(ss, off);
        const float rinv = rsqrtf(ss * (1.0f / 64.0f) + 1e-6f);
        p[lane] = out * rinv;
    }
}

// ---------------------------------------------------------------------------
// Causal flash attention. Block = 256 threads handles a 64-row Q tile of one
// (b, h). 4 threads per Q row (cs = column segment of 16 k-cols each).
// Online softmax; O partials in registers, combined via shfl at the end.
// y layout: (B*T, C) with head h at cols [h*64, h*64+64).
// ---------------------------------------------------------------------------
__global__ __launch_bounds__(256) void attn_fwd(const float* __restrict__ qkv,
                                                float* __restrict__ y) {
    const int qt = blockIdx.x;   // 0..31
    const int h  = blockIdx.y;   // 0..15
    const int b  = blockIdx.z;   // 0..3
    const int tid = threadIdx.x;
    const int r  = tid >> 2;     // 0..63 row within Q tile
    const int cs = tid & 3;      // 0..3

    __shared__ float Qs[64][65];
    __shared__ float Ks[64][65];
    __shared__ float Vs[64][65];

    {
        const float* qp = qkv + (size_t)(b * TT + qt * 64 + r) * (3 * CC) + h * DD + cs * 16;
#pragma unroll
        for (int c = 0; c < 16; ++c) Qs[r][cs * 16 + c] = qp[c];
    }

    float Opart[64];
#pragma unroll
    for (int d = 0; d < 64; ++d) Opart[d] = 0.f;
    float m_i = -1e30f, l_i = 0.f;
    const int gq = qt * 64 + r;

    for (int kt = 0; kt <= qt; ++kt) {
        __syncthreads();   // previous tile's reads done (and Qs visible, 1st iter)
        {
            const float* kp = qkv + (size_t)(b * TT + kt * 64 + r) * (3 * CC) + CC + h * DD + cs * 16;
#pragma unroll
            for (int c = 0; c < 16; ++c) {
                Ks[r][cs * 16 + c] = kp[c];
                Vs[r][cs * 16 + c] = kp[CC + c];
            }
        }
        __syncthreads();

        float sc[16];
#pragma unroll
        for (int jj = 0; jj < 16; ++jj) sc[jj] = 0.f;
        for (int d = 0; d < 64; ++d) {
            const float qd = Qs[r][d];
#pragma unroll
            for (int jj = 0; jj < 16; ++jj) sc[jj] += qd * Ks[cs * 16 + jj][d];
        }

        float mt = -1e30f;
#pragma unroll
        for (int jj = 0; jj < 16; ++jj) {
            const int gk = kt * 64 + cs * 16 + jj;
            sc[jj] = (gk <= gq) ? sc[jj] * 0.125f : -1e30f;
            mt = fmaxf(mt, sc[jj]);
        }
        mt = fmaxf(mt, __shfl_xor(mt, 1));
        mt = fmaxf(mt, __shfl_xor(mt, 2));
        const float m_new = fmaxf(m_i, mt);
        const float alpha = __expf(m_i - m_new);

        float p[16];
        float psum = 0.f;
#pragma unroll
        for (int jj = 0; jj < 16; ++jj) {
            p[jj] = __expf(sc[jj] - m_new);
            psum += p[jj];
        }
        psum += __shfl_xor(psum, 1);
        psum += __shfl_xor(psum, 2);
        l_i = l_i * alpha + psum;
        m_i = m_new;

        for (int d = 0; d < 64; ++d) {
            float acc = 0.f;
#pragma unroll
            for (int jj = 0; jj < 16; ++jj) acc += p[jj] * Vs[cs * 16 + jj][d];
            Opart[d] = Opart[d] * alpha + acc;
        }
    }

    // combine the 4 per-row partials
#pragma unroll
    for (int d = 0; d < 64; ++d) {
        float v = Opart[d];
        v += __shfl_xor(v, 1);
        v += __shfl_xor(v, 2);
        Opart[d] = v;
    }
    const float inv_l = 1.f / l_i;
    float* yp = y + (size_t)(b * TT + qt * 64 + r) * CC + h * DD;
#pragma unroll
    for (int c = 0; c < 16; ++c) yp[cs * 16 + c] = Opart[cs * 16 + c] * inv_l;
}

// ---------------------------------------------------------------------------
extern "C" void kernel_launch(void* const* d_in, const int* in_sizes, int n_in,
                              void* d_out, int out_size, void* d_ws, size_t ws_size,
                              hipStream_t stream) {
    const float* x      = (const float*)d_in[0];   // (4,2048,1024)
    const float* cosb   = (const float*)d_in[1];   // (1,2048,1,32)
    const float* sinb   = (const float*)d_in[2];
    const float* w_attn = (const float*)d_in[3];   // (3072,1024)
    const float* w_proj = (const float*)d_in[4];   // (1024,1024)
    float* out = (float*)d_out;                    // (4,2048,1024)

    float* qkv = (float*)d_ws;                        // 8192 x 3072 = 96 MB
    float* y   = qkv + (size_t)8192 * 3072;           // 8192 x 1024 = 32 MB

    // qkv = x @ w_attn^T
    gemm_abt<<<dim3(3072 / 128, 8192 / 128), 256, 0, stream>>>(
        x, w_attn, qkv, 8192, 3072, 1024);

    // rope + rmsnorm in place on q,k
    rope_rms<<<(8192 * HH) / 4, 256, 0, stream>>>(qkv, cosb, sinb);

    // causal attention -> y
    attn_fwd<<<dim3(TT / 64, HH, 4), 256, 0, stream>>>(qkv, y);

    // out = y @ w_proj^T
    gemm_abt<<<dim3(1024 / 128, 8192 / 128), 256, 0, stream>>>(
        y, w_proj, out, 8192, 1024, 1024);
}

// Round 2
// 1229.255 us; speedup vs baseline: 4.8793x; 4.8793x over previous
//
#include <hip/hip_runtime.h>
#include <hip/hip_bf16.h>
#include <math.h>

// Problem: B=4, T=2048, C=1024, H=16, D=64, d_half=32
// qkv = x @ w_attn^T   (8192 x 3072)
// rope+rmsnorm on q,k
// causal attention per (b,h)   <-- bf16 MFMA flash attention this round
// out = y @ w_proj^T   (8192 x 1024)

#define TT 2048
#define CC 1024
#define HH 16
#define DD 64

typedef __attribute__((ext_vector_type(8))) short short8;
typedef __attribute__((ext_vector_type(4))) float f32x4;

// fp32 -> bf16 (RNE, finite inputs only)
__device__ __forceinline__ unsigned short f2bf(float f) {
    unsigned u = __builtin_bit_cast(unsigned, f);
    u = (u + 0x7fffu + ((u >> 16) & 1u)) >> 16;
    return (unsigned short)u;
}

// ---------------------------------------------------------------------------
// Generic C[M,N] = A[M,K] * B[N,K]^T, fp32. BM=BN=128, BK=16, 256 thr, 8x8.
// ---------------------------------------------------------------------------
__global__ __launch_bounds__(256) void gemm_abt(const float* __restrict__ A,
                                                const float* __restrict__ B,
                                                float* __restrict__ C,
                                                int M, int N, int K) {
    __shared__ float As[16][128];   // k-major: As[kk][row]
    __shared__ float Bs[16][128];

    const int tid = threadIdx.x;
    const int tx = tid & 15;        // N direction (0..15)
    const int ty = tid >> 4;        // M direction (0..15)
    const int rowC = blockIdx.y * 128;
    const int colC = blockIdx.x * 128;

    const int r0 = tid >> 2;            // 0..63
    const int kc = (tid & 3) << 2;      // 0,4,8,12

    const float* Ap = A + (size_t)(rowC + r0) * K + kc;
    const float* Bp = B + (size_t)(colC + r0) * K + kc;
    const size_t rowStep = (size_t)64 * K;

    float acc[8][8];
#pragma unroll
    for (int i = 0; i < 8; ++i)
#pragma unroll
        for (int j = 0; j < 8; ++j) acc[i][j] = 0.f;

    for (int k0 = 0; k0 < K; k0 += 16) {
        float4 a0 = *(const float4*)(Ap + k0);
        float4 a1 = *(const float4*)(Ap + k0 + rowStep);
        float4 b0 = *(const float4*)(Bp + k0);
        float4 b1 = *(const float4*)(Bp + k0 + rowStep);
        __syncthreads();
        As[kc + 0][r0] = a0.x;  As[kc + 1][r0] = a0.y;
        As[kc + 2][r0] = a0.z;  As[kc + 3][r0] = a0.w;
        As[kc + 0][r0 + 64] = a1.x;  As[kc + 1][r0 + 64] = a1.y;
        As[kc + 2][r0 + 64] = a1.z;  As[kc + 3][r0 + 64] = a1.w;
        Bs[kc + 0][r0] = b0.x;  Bs[kc + 1][r0] = b0.y;
        Bs[kc + 2][r0] = b0.z;  Bs[kc + 3][r0] = b0.w;
        Bs[kc + 0][r0 + 64] = b1.x;  Bs[kc + 1][r0 + 64] = b1.y;
        Bs[kc + 2][r0 + 64] = b1.z;  Bs[kc + 3][r0 + 64] = b1.w;
        __syncthreads();
#pragma unroll
        for (int kk = 0; kk < 16; ++kk) {
            float4 av0 = *(const float4*)&As[kk][ty * 8];
            float4 av1 = *(const float4*)&As[kk][ty * 8 + 4];
            float4 bv0 = *(const float4*)&Bs[kk][tx * 8];
            float4 bv1 = *(const float4*)&Bs[kk][tx * 8 + 4];
            float a[8] = {av0.x, av0.y, av0.z, av0.w, av1.x, av1.y, av1.z, av1.w};
            float b[8] = {bv0.x, bv0.y, bv0.z, bv0.w, bv1.x, bv1.y, bv1.z, bv1.w};
#pragma unroll
            for (int i = 0; i < 8; ++i)
#pragma unroll
                for (int j = 0; j < 8; ++j)
                    acc[i][j] += a[i] * b[j];
        }
    }

#pragma unroll
    for (int i = 0; i < 8; ++i) {
        float* Cp = C + (size_t)(rowC + ty * 8 + i) * N + colC + tx * 8;
        float4 w0 = {acc[i][0], acc[i][1], acc[i][2], acc[i][3]};
        float4 w1 = {acc[i][4], acc[i][5], acc[i][6], acc[i][7]};
        ((float4*)Cp)[0] = w0;
        ((float4*)Cp)[1] = w1;
    }
}

// ---------------------------------------------------------------------------
// RoPE + RMSNorm applied in-place to q and k inside qkv (8192 x 3072).
// One wave (64 lanes) per (m, h); lane = d in [0,64).
// ---------------------------------------------------------------------------
__global__ __launch_bounds__(256) void rope_rms(float* __restrict__ qkv,
                                                const float* __restrict__ cosb,
                                                const float* __restrict__ sinb) {
    const int wave = (blockIdx.x * 256 + threadIdx.x) >> 6;
    const int lane = threadIdx.x & 63;
    const int h = wave & (HH - 1);
    const int m = wave >> 4;                // 0..8191 (b*T + t)
    const int t = m & (TT - 1);
    const int j = lane & 31;
    const float c = cosb[t * 32 + j];
    const float s = sinb[t * 32 + j];
    float* qp = qkv + (size_t)m * (3 * CC) + h * DD;

#pragma unroll
    for (int which = 0; which < 2; ++which) {   // 0 = q, 1 = k
        float* p = qp + which * CC;
        const float x1 = p[j];
        const float x2 = p[j + 32];
        float out = (lane < 32) ? (x1 * c + x2 * s) : (x2 * c - x1 * s);
        float ss = out * out;
#pragma unroll
        for (int off = 32; off > 0; off >>= 1) ss += __shfl_xor(ss, off);
        const float rinv = rsqrtf(ss * (1.0f / 64.0f) + 1e-6f);
        p[lane] = out * rinv;
    }
}

// ---------------------------------------------------------------------------
// bf16 MFMA flash attention. Block = 256 thr (4 waves) per (b, h, 64-row Q
// tile). Wave w owns Q rows [w*16, w*16+16). Per 64-key tile: stage K row-
// major + V transposed into LDS (bf16, stride 72 to break bank aliasing),
// QK^T and PV via mfma_f32_16x16x32_bf16, online softmax in C-layout regs,
// P re-enters A-layout via a per-wave LDS round trip.
// ---------------------------------------------------------------------------
__global__ __launch_bounds__(256) void attn_mfma(const float* __restrict__ qkv,
                                                 float* __restrict__ y) {
    const int qt = blockIdx.x;   // 0..31
    const int h  = blockIdx.y;   // 0..15
    const int b  = blockIdx.z;   // 0..3
    const int tid  = threadIdx.x;
    const int w    = tid >> 6;       // wave 0..3
    const int lane = tid & 63;
    const int quad = lane >> 4;      // 0..3
    const int lm   = lane & 15;      // 0..15

    __shared__ unsigned short Ks[64][72];   // K[n][d]   bf16
    __shared__ unsigned short Vt[64][72];   // V^T[d][n] bf16
    __shared__ unsigned short Ps[4][16][72];// per-wave P[m][n] bf16

    // ---- Q fragments for this wave's 16 rows (A-layout), loaded once ----
    short8 qf[2];
    {
        const float* qp = qkv + (size_t)(b * TT + qt * 64 + w * 16 + lm) * (3 * CC) + h * DD;
#pragma unroll
        for (int kk = 0; kk < 2; ++kk) {
            const float* p = qp + kk * 32 + quad * 8;
            float4 f0 = ((const float4*)p)[0];
            float4 f1 = ((const float4*)p)[1];
            short8 v;
            v[0] = (short)f2bf(f0.x); v[1] = (short)f2bf(f0.y);
            v[2] = (short)f2bf(f0.z); v[3] = (short)f2bf(f0.w);
            v[4] = (short)f2bf(f1.x); v[5] = (short)f2bf(f1.y);
            v[6] = (short)f2bf(f1.z); v[7] = (short)f2bf(f1.w);
            qf[kk] = v;
        }
    }

    f32x4 Oacc[4];
#pragma unroll
    for (int dt = 0; dt < 4; ++dt) Oacc[dt] = (f32x4){0.f, 0.f, 0.f, 0.f};
    float m_i[4] = {-3e38f, -3e38f, -3e38f, -3e38f};
    float l_i[4] = {0.f, 0.f, 0.f, 0.f};

    // staging assignment: row n = tid>>2, d-segment = (tid&3)*16
    const int sn = tid >> 2;
    const int sd = (tid & 3) * 16;

    for (int kt = 0; kt <= qt; ++kt) {
        __syncthreads();   // previous tile's LDS reads done
        {
            const float* kp = qkv + (size_t)(b * TT + kt * 64 + sn) * (3 * CC) + CC + h * DD + sd;
#pragma unroll
            for (int jj = 0; jj < 4; ++jj) {
                float4 kv = ((const float4*)kp)[jj];
                float4 vv = ((const float4*)(kp + CC))[jj];
                Ks[sn][sd + jj * 4 + 0] = f2bf(kv.x);
                Ks[sn][sd + jj * 4 + 1] = f2bf(kv.y);
                Ks[sn][sd + jj * 4 + 2] = f2bf(kv.z);
                Ks[sn][sd + jj * 4 + 3] = f2bf(kv.w);
                Vt[sd + jj * 4 + 0][sn] = f2bf(vv.x);
                Vt[sd + jj * 4 + 1][sn] = f2bf(vv.y);
                Vt[sd + jj * 4 + 2][sn] = f2bf(vv.z);
                Vt[sd + jj * 4 + 3][sn] = f2bf(vv.w);
            }
        }
        __syncthreads();

        // ---- S = Q K^T (16 x 64 per wave) ----
        f32x4 sf[4];
#pragma unroll
        for (int nt = 0; nt < 4; ++nt) sf[nt] = (f32x4){0.f, 0.f, 0.f, 0.f};
#pragma unroll
        for (int kk = 0; kk < 2; ++kk)
#pragma unroll
            for (int nt = 0; nt < 4; ++nt) {
                short8 kf = *(const short8*)&Ks[nt * 16 + lm][kk * 32 + quad * 8];
                sf[nt] = __builtin_amdgcn_mfma_f32_16x16x32_bf16(qf[kk], kf, sf[nt], 0, 0, 0);
            }

        // ---- online softmax (C layout: row = quad*4+r, col = nt*16+lm) ----
        const int rowg0 = qt * 64 + w * 16 + quad * 4;
        const int colg0 = kt * 64 + lm;
#pragma unroll
        for (int r = 0; r < 4; ++r) {
            const int rowg = rowg0 + r;
            float mx = m_i[r];
#pragma unroll
            for (int nt = 0; nt < 4; ++nt) {
                float s = sf[nt][r] * 0.125f;
                s = (colg0 + nt * 16 <= rowg) ? s : -3e38f;
                sf[nt][r] = s;
                mx = fmaxf(mx, s);
            }
            mx = fmaxf(mx, __shfl_xor(mx, 1));
            mx = fmaxf(mx, __shfl_xor(mx, 2));
            mx = fmaxf(mx, __shfl_xor(mx, 4));
            mx = fmaxf(mx, __shfl_xor(mx, 8));
            const float alpha = __expf(m_i[r] - mx);
            float psum = 0.f;
#pragma unroll
            for (int nt = 0; nt < 4; ++nt) {
                float p = __expf(sf[nt][r] - mx);
                Ps[w][quad * 4 + r][nt * 16 + lm] = f2bf(p);
                psum += p;
            }
            psum += __shfl_xor(psum, 1);
            psum += __shfl_xor(psum, 2);
            psum += __shfl_xor(psum, 4);
            psum += __shfl_xor(psum, 8);
            l_i[r] = l_i[r] * alpha + psum;
            m_i[r] = mx;
#pragma unroll
            for (int dt = 0; dt < 4; ++dt) Oacc[dt][r] *= alpha;
        }

        // ---- O += P V  (P from per-wave LDS in A-layout, V^T contiguous) ----
#pragma unroll
        for (int kk = 0; kk < 2; ++kk) {
            short8 pf = *(const short8*)&Ps[w][lm][kk * 32 + quad * 8];
#pragma unroll
            for (int dt = 0; dt < 4; ++dt) {
                short8 vf = *(const short8*)&Vt[dt * 16 + lm][kk * 32 + quad * 8];
                Oacc[dt] = __builtin_amdgcn_mfma_f32_16x16x32_bf16(pf, vf, Oacc[dt], 0, 0, 0);
            }
        }
    }

    // ---- epilogue: divide by l, store ----
#pragma unroll
    for (int r = 0; r < 4; ++r) {
        const float inv_l = 1.f / l_i[r];
        float* yp = y + (size_t)(b * TT + qt * 64 + w * 16 + quad * 4 + r) * CC + h * DD + lm;
#pragma unroll
        for (int dt = 0; dt < 4; ++dt) yp[dt * 16] = Oacc[dt][r] * inv_l;
    }
}

// ---------------------------------------------------------------------------
extern "C" void kernel_launch(void* const* d_in, const int* in_sizes, int n_in,
                              void* d_out, int out_size, void* d_ws, size_t ws_size,
                              hipStream_t stream) {
    const float* x      = (const float*)d_in[0];   // (4,2048,1024)
    const float* cosb   = (const float*)d_in[1];   // (1,2048,1,32)
    const float* sinb   = (const float*)d_in[2];
    const float* w_attn = (const float*)d_in[3];   // (3072,1024)
    const float* w_proj = (const float*)d_in[4];   // (1024,1024)
    float* out = (float*)d_out;                    // (4,2048,1024)

    float* qkv = (float*)d_ws;                        // 8192 x 3072 = 96 MB
    float* y   = qkv + (size_t)8192 * 3072;           // 8192 x 1024 = 32 MB

    // qkv = x @ w_attn^T
    gemm_abt<<<dim3(3072 / 128, 8192 / 128), 256, 0, stream>>>(
        x, w_attn, qkv, 8192, 3072, 1024);

    // rope + rmsnorm in place on q,k
    rope_rms<<<(8192 * HH) / 4, 256, 0, stream>>>(qkv, cosb, sinb);

    // causal attention -> y (bf16 MFMA)
    attn_mfma<<<dim3(TT / 64, HH, 4), 256, 0, stream>>>(qkv, y);

    // out = y @ w_proj^T
    gemm_abt<<<dim3(1024 / 128, 8192 / 128), 256, 0, stream>>>(
        y, w_proj, out, 8192, 1024, 1024);
}

// Round 3
// 475.249 us; speedup vs baseline: 12.6207x; 2.5866x over previous
//
#include <hip/hip_runtime.h>
#include <hip/hip_bf16.h>
#include <math.h>

// Problem: B=4, T=2048, C=1024, H=16, D=64, d_half=32
// Dataflow (all-bf16 internal):
//   cast x, w_attn, w_proj -> bf16
//   qkvb = xb @ wab^T            (bf16 MFMA GEMM, bf16 out)
//   rope+rmsnorm in place on q,k (bf16 storage, fp32 math)
//   attn (bf16 MFMA flash)  -> yb (bf16)
//   out  = yb @ wpb^T            (bf16 MFMA GEMM, fp32 out)

#define TT 2048
#define CC 1024
#define HH 16
#define DD 64

typedef __attribute__((ext_vector_type(8))) short short8;
typedef __attribute__((ext_vector_type(4))) float f32x4;
typedef unsigned short ushort_t;

// fp32 -> bf16 (RNE, finite inputs only)
__device__ __forceinline__ ushort_t f2bf(float f) {
    unsigned u = __builtin_bit_cast(unsigned, f);
    u = (u + 0x7fffu + ((u >> 16) & 1u)) >> 16;
    return (ushort_t)u;
}
__device__ __forceinline__ float bf2f(ushort_t u) {
    return __builtin_bit_cast(float, (unsigned)u << 16);
}

// ---------------------------------------------------------------------------
// float -> bf16 cast, 8 elements/thread
// ---------------------------------------------------------------------------
__global__ __launch_bounds__(256) void cast_bf16(const float* __restrict__ in,
                                                 ushort_t* __restrict__ out, int n8) {
    const int i = blockIdx.x * 256 + threadIdx.x;
    if (i >= n8) return;
    const float4* p = (const float4*)in + (size_t)i * 2;
    float4 f0 = p[0], f1 = p[1];
    short8 v;
    v[0] = (short)f2bf(f0.x); v[1] = (short)f2bf(f0.y);
    v[2] = (short)f2bf(f0.z); v[3] = (short)f2bf(f0.w);
    v[4] = (short)f2bf(f1.x); v[5] = (short)f2bf(f1.y);
    v[6] = (short)f2bf(f1.z); v[7] = (short)f2bf(f1.w);
    *(short8*)(out + (size_t)i * 8) = v;
}

// ---------------------------------------------------------------------------
// bf16 MFMA GEMM: C[M,N] = A[M,K] * B[N,K]^T.  m97 structure:
// 128x128 tile, BK=32, 256 thr = 4 waves in 2x2, each wave 64x64 (16 MFMA/it),
// global_load_lds width-16 staging, unpadded k-major LDS.
// OUTF32: write float C, else bf16 C.
// ---------------------------------------------------------------------------
template <bool OUTF32>
__global__ __launch_bounds__(256) void gemm_bt(const ushort_t* __restrict__ A,
                                               const ushort_t* __restrict__ B,
                                               void* __restrict__ C,
                                               int M, int N, int K) {
    __shared__ ushort_t As[128 * 32];
    __shared__ ushort_t Bs[128 * 32];

    const int tid  = threadIdx.x;
    const int wv   = tid >> 6;
    const int ln   = tid & 63;
    const int quad = ln >> 4;
    const int lm   = ln & 15;
    const int wm   = wv & 1;       // wave row (2x2 wave grid)
    const int wn   = wv >> 1;      // wave col
    const int rowC = blockIdx.y * 128;
    const int colC = blockIdx.x * 128;

    // staging: lane covers row = half*64 + wv*16 + (ln>>2), k-quarter = ln&3
    const int srow = wv * 16 + (ln >> 2);
    const int skq  = (ln & 3) * 8;            // bf16 elems

    f32x4 acc[4][4];
#pragma unroll
    for (int i = 0; i < 4; ++i)
#pragma unroll
        for (int j = 0; j < 4; ++j) acc[i][j] = (f32x4){0.f, 0.f, 0.f, 0.f};

    for (int k0 = 0; k0 < K; k0 += 32) {
        __syncthreads();
#pragma unroll
        for (int half = 0; half < 2; ++half) {
            const ushort_t* gA = A + (size_t)(rowC + half * 64 + srow) * K + k0 + skq;
            const ushort_t* gB = B + (size_t)(colC + half * 64 + srow) * K + k0 + skq;
            ushort_t* lA = As + (half * 64 + wv * 16) * 32;   // wave-uniform base
            ushort_t* lB = Bs + (half * 64 + wv * 16) * 32;
            __builtin_amdgcn_global_load_lds(
                (const __attribute__((address_space(1))) unsigned int*)gA,
                (__attribute__((address_space(3))) unsigned int*)lA, 16, 0, 0);
            __builtin_amdgcn_global_load_lds(
                (const __attribute__((address_space(1))) unsigned int*)gB,
                (__attribute__((address_space(3))) unsigned int*)lB, 16, 0, 0);
        }
        __syncthreads();

        short8 af[4], bf[4];
#pragma unroll
        for (int mt = 0; mt < 4; ++mt)
            af[mt] = *(const short8*)&As[(wm * 64 + mt * 16 + lm) * 32 + quad * 8];
#pragma unroll
        for (int nt = 0; nt < 4; ++nt)
            bf[nt] = *(const short8*)&Bs[(wn * 64 + nt * 16 + lm) * 32 + quad * 8];
#pragma unroll
        for (int mt = 0; mt < 4; ++mt)
#pragma unroll
            for (int nt = 0; nt < 4; ++nt)
                acc[mt][nt] = __builtin_amdgcn_mfma_f32_16x16x32_bf16(
                    af[mt], bf[nt], acc[mt][nt], 0, 0, 0);
    }

    // epilogue: C layout row = quad*4 + r, col = lm within each 16x16 tile
#pragma unroll
    for (int mt = 0; mt < 4; ++mt)
#pragma unroll
        for (int r = 0; r < 4; ++r) {
            const size_t row = rowC + wm * 64 + mt * 16 + quad * 4 + r;
#pragma unroll
            for (int nt = 0; nt < 4; ++nt) {
                const size_t col = colC + wn * 64 + nt * 16 + lm;
                if (OUTF32) ((float*)C)[row * N + col] = acc[mt][nt][r];
                else        ((ushort_t*)C)[row * N + col] = f2bf(acc[mt][nt][r]);
            }
        }
}

// ---------------------------------------------------------------------------
// RoPE + RMSNorm in-place on bf16 qkv (8192 x 3072). One wave per (m, h).
// ---------------------------------------------------------------------------
__global__ __launch_bounds__(256) void rope_rms(ushort_t* __restrict__ qkv,
                                                const float* __restrict__ cosb,
                                                const float* __restrict__ sinb) {
    const int wave = (blockIdx.x * 256 + threadIdx.x) >> 6;
    const int lane = threadIdx.x & 63;
    const int h = wave & (HH - 1);
    const int m = wave >> 4;                // 0..8191
    const int t = m & (TT - 1);
    const int j = lane & 31;
    const float c = cosb[t * 32 + j];
    const float s = sinb[t * 32 + j];
    ushort_t* qp = qkv + (size_t)m * (3 * CC) + h * DD;

#pragma unroll
    for (int which = 0; which < 2; ++which) {   // 0 = q, 1 = k
        ushort_t* p = qp + which * CC;
        const float x1 = bf2f(p[j]);
        const float x2 = bf2f(p[j + 32]);
        float out = (lane < 32) ? (x1 * c + x2 * s) : (x2 * c - x1 * s);
        float ss = out * out;
#pragma unroll
        for (int off = 32; off > 0; off >>= 1) ss += __shfl_xor(ss, off);
        const float rinv = rsqrtf(ss * (1.0f / 64.0f) + 1e-6f);
        p[lane] = f2bf(out * rinv);
    }
}

// ---------------------------------------------------------------------------
// bf16 MFMA flash attention (qkv bf16 in, y bf16 out). Same structure as
// round 2, minus all f2bf conversion in staging.
// ---------------------------------------------------------------------------
__global__ __launch_bounds__(256) void attn_mfma(const ushort_t* __restrict__ qkv,
                                                 ushort_t* __restrict__ y) {
    const int qt = blockIdx.x;   // 0..31
    const int h  = blockIdx.y;   // 0..15
    const int b  = blockIdx.z;   // 0..3
    const int tid  = threadIdx.x;
    const int w    = tid >> 6;       // wave 0..3
    const int lane = tid & 63;
    const int quad = lane >> 4;
    const int lm   = lane & 15;

    __shared__ ushort_t Ks[64][72];    // K[n][d]
    __shared__ ushort_t Vt[64][72];    // V^T[d][n]
    __shared__ ushort_t Ps[4][16][72]; // per-wave P[m][n]

    short8 qf[2];
    {
        const ushort_t* qp = qkv + (size_t)(b * TT + qt * 64 + w * 16 + lm) * (3 * CC) + h * DD;
        qf[0] = *(const short8*)(qp + quad * 8);
        qf[1] = *(const short8*)(qp + 32 + quad * 8);
    }

    f32x4 Oacc[4];
#pragma unroll
    for (int dt = 0; dt < 4; ++dt) Oacc[dt] = (f32x4){0.f, 0.f, 0.f, 0.f};
    float m_i[4] = {-3e38f, -3e38f, -3e38f, -3e38f};
    float l_i[4] = {0.f, 0.f, 0.f, 0.f};

    const int sn = tid >> 2;           // staged row
    const int sd = (tid & 3) * 16;     // d-segment

    for (int kt = 0; kt <= qt; ++kt) {
        __syncthreads();
        {
            const ushort_t* kp = qkv + (size_t)(b * TT + kt * 64 + sn) * (3 * CC) + CC + h * DD + sd;
            short8 k0v = *(const short8*)kp;
            short8 k1v = *(const short8*)(kp + 8);
            short8 v0v = *(const short8*)(kp + CC);
            short8 v1v = *(const short8*)(kp + CC + 8);
            *(short8*)&Ks[sn][sd]     = k0v;
            *(short8*)&Ks[sn][sd + 8] = k1v;
#pragma unroll
            for (int jj = 0; jj < 8; ++jj) {
                Vt[sd + jj][sn]     = (ushort_t)v0v[jj];
                Vt[sd + 8 + jj][sn] = (ushort_t)v1v[jj];
            }
        }
        __syncthreads();

        // ---- S = Q K^T ----
        f32x4 sf[4];
#pragma unroll
        for (int nt = 0; nt < 4; ++nt) sf[nt] = (f32x4){0.f, 0.f, 0.f, 0.f};
#pragma unroll
        for (int kk = 0; kk < 2; ++kk)
#pragma unroll
            for (int nt = 0; nt < 4; ++nt) {
                short8 kf = *(const short8*)&Ks[nt * 16 + lm][kk * 32 + quad * 8];
                sf[nt] = __builtin_amdgcn_mfma_f32_16x16x32_bf16(qf[kk], kf, sf[nt], 0, 0, 0);
            }

        // ---- online softmax ----
        const int rowg0 = qt * 64 + w * 16 + quad * 4;
        const int colg0 = kt * 64 + lm;
#pragma unroll
        for (int r = 0; r < 4; ++r) {
            const int rowg = rowg0 + r;
            float mx = m_i[r];
#pragma unroll
            for (int nt = 0; nt < 4; ++nt) {
                float s = sf[nt][r] * 0.125f;
                s = (colg0 + nt * 16 <= rowg) ? s : -3e38f;
                sf[nt][r] = s;
                mx = fmaxf(mx, s);
            }
            mx = fmaxf(mx, __shfl_xor(mx, 1));
            mx = fmaxf(mx, __shfl_xor(mx, 2));
            mx = fmaxf(mx, __shfl_xor(mx, 4));
            mx = fmaxf(mx, __shfl_xor(mx, 8));
            const float alpha = __expf(m_i[r] - mx);
            float psum = 0.f;
#pragma unroll
            for (int nt = 0; nt < 4; ++nt) {
                float p = __expf(sf[nt][r] - mx);
                Ps[w][quad * 4 + r][nt * 16 + lm] = f2bf(p);
                psum += p;
            }
            psum += __shfl_xor(psum, 1);
            psum += __shfl_xor(psum, 2);
            psum += __shfl_xor(psum, 4);
            psum += __shfl_xor(psum, 8);
            l_i[r] = l_i[r] * alpha + psum;
            m_i[r] = mx;
#pragma unroll
            for (int dt = 0; dt < 4; ++dt) Oacc[dt][r] *= alpha;
        }

        // ---- O += P V ----
#pragma unroll
        for (int kk = 0; kk < 2; ++kk) {
            short8 pf = *(const short8*)&Ps[w][lm][kk * 32 + quad * 8];
#pragma unroll
            for (int dt = 0; dt < 4; ++dt) {
                short8 vf = *(const short8*)&Vt[dt * 16 + lm][kk * 32 + quad * 8];
                Oacc[dt] = __builtin_amdgcn_mfma_f32_16x16x32_bf16(pf, vf, Oacc[dt], 0, 0, 0);
            }
        }
    }

    // ---- epilogue ----
#pragma unroll
    for (int r = 0; r < 4; ++r) {
        const float inv_l = 1.f / l_i[r];
        ushort_t* yp = y + (size_t)(b * TT + qt * 64 + w * 16 + quad * 4 + r) * CC + h * DD + lm;
#pragma unroll
        for (int dt = 0; dt < 4; ++dt) yp[dt * 16] = f2bf(Oacc[dt][r] * inv_l);
    }
}

// ---------------------------------------------------------------------------
extern "C" void kernel_launch(void* const* d_in, const int* in_sizes, int n_in,
                              void* d_out, int out_size, void* d_ws, size_t ws_size,
                              hipStream_t stream) {
    const float* x      = (const float*)d_in[0];   // (4,2048,1024)
    const float* cosb   = (const float*)d_in[1];   // (1,2048,1,32)
    const float* sinb   = (const float*)d_in[2];
    const float* w_attn = (const float*)d_in[3];   // (3072,1024)
    const float* w_proj = (const float*)d_in[4];   // (1024,1024)
    float* out = (float*)d_out;                    // (4,2048,1024)

    // workspace layout (bf16 elements)
    ushort_t* qkvb = (ushort_t*)d_ws;                       // 8192*3072
    ushort_t* yb   = qkvb + (size_t)8192 * 3072;            // 8192*1024
    ushort_t* xb   = yb   + (size_t)8192 * 1024;            // 8192*1024
    ushort_t* wab  = xb   + (size_t)8192 * 1024;            // 3072*1024
    ushort_t* wpb  = wab  + (size_t)3072 * 1024;            // 1024*1024

    // casts
    cast_bf16<<<(8192 * 1024 / 8 + 255) / 256, 256, 0, stream>>>(x, xb, 8192 * 1024 / 8);
    cast_bf16<<<(3072 * 1024 / 8 + 255) / 256, 256, 0, stream>>>(w_attn, wab, 3072 * 1024 / 8);
    cast_bf16<<<(1024 * 1024 / 8 + 255) / 256, 256, 0, stream>>>(w_proj, wpb, 1024 * 1024 / 8);

    // qkv = x @ w_attn^T   (bf16 out)
    gemm_bt<false><<<dim3(3072 / 128, 8192 / 128), 256, 0, stream>>>(
        xb, wab, qkvb, 8192, 3072, 1024);

    // rope + rmsnorm in place on q,k
    rope_rms<<<(8192 * HH) / 4, 256, 0, stream>>>(qkvb, cosb, sinb);

    // causal attention -> yb
    attn_mfma<<<dim3(TT / 64, HH, 4), 256, 0, stream>>>(qkvb, yb);

    // out = y @ w_proj^T   (fp32 out)
    gemm_bt<true><<<dim3(1024 / 128, 8192 / 128), 256, 0, stream>>>(
        yb, wpb, out, 8192, 1024, 1024);
}

// Round 4
// 309.659 us; speedup vs baseline: 19.3696x; 1.5348x over previous
//
#include <hip/hip_runtime.h>
#include <hip/hip_bf16.h>
#include <math.h>

// Problem: B=4, T=2048, C=1024, H=16, D=64, d_half=32
// Dataflow:
//   cast x, w_attn, w_proj -> bf16
//   qkvb = xb @ wab^T  with rope+rmsnorm fused into the q/k epilogue (bf16 out)
//   attn (bf16 MFMA flash, fixed-max softmax, fold-paired q-tiles) -> yb
//   out  = yb @ wpb^T  (fp32 out)

#define TT 2048
#define CC 1024
#define HH 16
#define DD 64

typedef __attribute__((ext_vector_type(8))) short short8;
typedef __attribute__((ext_vector_type(4))) float f32x4;
typedef unsigned short ushort_t;

// fp32 -> bf16 (RNE, finite inputs only)
__device__ __forceinline__ ushort_t f2bf(float f) {
    unsigned u = __builtin_bit_cast(unsigned, f);
    u = (u + 0x7fffu + ((u >> 16) & 1u)) >> 16;
    return (ushort_t)u;
}

// ---------------------------------------------------------------------------
// float -> bf16 cast, 8 elements/thread
// ---------------------------------------------------------------------------
__global__ __launch_bounds__(256) void cast_bf16(const float* __restrict__ in,
                                                 ushort_t* __restrict__ out, int n8) {
    const int i = blockIdx.x * 256 + threadIdx.x;
    if (i >= n8) return;
    const float4* p = (const float4*)in + (size_t)i * 2;
    float4 f0 = p[0], f1 = p[1];
    short8 v;
    v[0] = (short)f2bf(f0.x); v[1] = (short)f2bf(f0.y);
    v[2] = (short)f2bf(f0.z); v[3] = (short)f2bf(f0.w);
    v[4] = (short)f2bf(f1.x); v[5] = (short)f2bf(f1.y);
    v[6] = (short)f2bf(f1.z); v[7] = (short)f2bf(f1.w);
    *(short8*)(out + (size_t)i * 8) = v;
}

// ---------------------------------------------------------------------------
// bf16 MFMA GEMM (m97 structure): C = A[M,K] * B[N,K]^T, 128x128 tile, BK=32.
// OUTF32 selects fp32 vs bf16 C.
// ---------------------------------------------------------------------------
template <bool OUTF32>
__global__ __launch_bounds__(256) void gemm_bt(const ushort_t* __restrict__ A,
                                               const ushort_t* __restrict__ B,
                                               void* __restrict__ C,
                                               int M, int N, int K) {
    __shared__ ushort_t As[128 * 32];
    __shared__ ushort_t Bs[128 * 32];

    const int tid  = threadIdx.x;
    const int wv   = tid >> 6;
    const int ln   = tid & 63;
    const int quad = ln >> 4;
    const int lm   = ln & 15;
    const int wm   = wv & 1;
    const int wn   = wv >> 1;
    const int rowC = blockIdx.y * 128;
    const int colC = blockIdx.x * 128;

    const int srow = wv * 16 + (ln >> 2);
    const int skq  = (ln & 3) * 8;

    f32x4 acc[4][4];
#pragma unroll
    for (int i = 0; i < 4; ++i)
#pragma unroll
        for (int j = 0; j < 4; ++j) acc[i][j] = (f32x4){0.f, 0.f, 0.f, 0.f};

    for (int k0 = 0; k0 < K; k0 += 32) {
        __syncthreads();
#pragma unroll
        for (int half = 0; half < 2; ++half) {
            const ushort_t* gA = A + (size_t)(rowC + half * 64 + srow) * K + k0 + skq;
            const ushort_t* gB = B + (size_t)(colC + half * 64 + srow) * K + k0 + skq;
            ushort_t* lA = As + (half * 64 + wv * 16) * 32;
            ushort_t* lB = Bs + (half * 64 + wv * 16) * 32;
            __builtin_amdgcn_global_load_lds(
                (const __attribute__((address_space(1))) unsigned int*)gA,
                (__attribute__((address_space(3))) unsigned int*)lA, 16, 0, 0);
            __builtin_amdgcn_global_load_lds(
                (const __attribute__((address_space(1))) unsigned int*)gB,
                (__attribute__((address_space(3))) unsigned int*)lB, 16, 0, 0);
        }
        __syncthreads();

        short8 af[4], bf[4];
#pragma unroll
        for (int mt = 0; mt < 4; ++mt)
            af[mt] = *(const short8*)&As[(wm * 64 + mt * 16 + lm) * 32 + quad * 8];
#pragma unroll
        for (int nt = 0; nt < 4; ++nt)
            bf[nt] = *(const short8*)&Bs[(wn * 64 + nt * 16 + lm) * 32 + quad * 8];
#pragma unroll
        for (int mt = 0; mt < 4; ++mt)
#pragma unroll
            for (int nt = 0; nt < 4; ++nt)
                acc[mt][nt] = __builtin_amdgcn_mfma_f32_16x16x32_bf16(
                    af[mt], bf[nt], acc[mt][nt], 0, 0, 0);
    }

#pragma unroll
    for (int mt = 0; mt < 4; ++mt)
#pragma unroll
        for (int r = 0; r < 4; ++r) {
            const size_t row = rowC + wm * 64 + mt * 16 + quad * 4 + r;
#pragma unroll
            for (int nt = 0; nt < 4; ++nt) {
                const size_t col = colC + wn * 64 + nt * 16 + lm;
                if (OUTF32) ((float*)C)[row * N + col] = acc[mt][nt][r];
                else        ((ushort_t*)C)[row * N + col] = f2bf(acc[mt][nt][r]);
            }
        }
}

// ---------------------------------------------------------------------------
// GEMM1 with fused rope+rmsnorm epilogue: C = A[M,K] * B[N,K]^T where B rows
// 0..2047 are w_q/w_k (rope+rms applied) and 2048.. are w_v (plain).
// A wave's 64-col slice is exactly one head; rope pair (d, d+32) is nt^2
// (in-lane); rotation preserves the row norm so rms comes from fp32 acc.
// ---------------------------------------------------------------------------
__global__ __launch_bounds__(256) void gemm_qkv(const ushort_t* __restrict__ A,
                                                const ushort_t* __restrict__ B,
                                                ushort_t* __restrict__ C,
                                                const float* __restrict__ cosb,
                                                const float* __restrict__ sinb,
                                                int M, int N, int K) {
    __shared__ ushort_t As[128 * 32];
    __shared__ ushort_t Bs[128 * 32];

    const int tid  = threadIdx.x;
    const int wv   = tid >> 6;
    const int ln   = tid & 63;
    const int quad = ln >> 4;
    const int lm   = ln & 15;
    const int wm   = wv & 1;
    const int wn   = wv >> 1;
    const int rowC = blockIdx.y * 128;
    const int colC = blockIdx.x * 128;

    const int srow = wv * 16 + (ln >> 2);
    const int skq  = (ln & 3) * 8;

    f32x4 acc[4][4];
#pragma unroll
    for (int i = 0; i < 4; ++i)
#pragma unroll
        for (int j = 0; j < 4; ++j) acc[i][j] = (f32x4){0.f, 0.f, 0.f, 0.f};

    for (int k0 = 0; k0 < K; k0 += 32) {
        __syncthreads();
#pragma unroll
        for (int half = 0; half < 2; ++half) {
            const ushort_t* gA = A + (size_t)(rowC + half * 64 + srow) * K + k0 + skq;
            const ushort_t* gB = B + (size_t)(colC + half * 64 + srow) * K + k0 + skq;
            ushort_t* lA = As + (half * 64 + wv * 16) * 32;
            ushort_t* lB = Bs + (half * 64 + wv * 16) * 32;
            __builtin_amdgcn_global_load_lds(
                (const __attribute__((address_space(1))) unsigned int*)gA,
                (__attribute__((address_space(3))) unsigned int*)lA, 16, 0, 0);
            __builtin_amdgcn_global_load_lds(
                (const __attribute__((address_space(1))) unsigned int*)gB,
                (__attribute__((address_space(3))) unsigned int*)lB, 16, 0, 0);
        }
        __syncthreads();

        short8 af[4], bf[4];
#pragma unroll
        for (int mt = 0; mt < 4; ++mt)
            af[mt] = *(const short8*)&As[(wm * 64 + mt * 16 + lm) * 32 + quad * 8];
#pragma unroll
        for (int nt = 0; nt < 4; ++nt)
            bf[nt] = *(const short8*)&Bs[(wn * 64 + nt * 16 + lm) * 32 + quad * 8];
#pragma unroll
        for (int mt = 0; mt < 4; ++mt)
#pragma unroll
            for (int nt = 0; nt < 4; ++nt)
                acc[mt][nt] = __builtin_amdgcn_mfma_f32_16x16x32_bf16(
                    af[mt], bf[nt], acc[mt][nt], 0, 0, 0);
    }

    const bool isqk = colC < 2 * CC;   // q or k section
#pragma unroll
    for (int mt = 0; mt < 4; ++mt)
#pragma unroll
        for (int r = 0; r < 4; ++r) {
            const int row = rowC + wm * 64 + mt * 16 + quad * 4 + r;
            ushort_t* Cp = C + (size_t)row * N + colC + wn * 64 + lm;
            if (isqk) {
                const int t = row & (TT - 1);
                float ss = 0.f;
#pragma unroll
                for (int nt = 0; nt < 4; ++nt) ss += acc[mt][nt][r] * acc[mt][nt][r];
                ss += __shfl_xor(ss, 1);
                ss += __shfl_xor(ss, 2);
                ss += __shfl_xor(ss, 4);
                ss += __shfl_xor(ss, 8);
                const float rinv = rsqrtf(ss * (1.0f / 64.0f) + 1e-6f);
                const float c0 = cosb[t * 32 + lm];
                const float c1 = cosb[t * 32 + 16 + lm];
                const float s0 = sinb[t * 32 + lm];
                const float s1 = sinb[t * 32 + 16 + lm];
                const float o0 = acc[mt][0][r] * c0 + acc[mt][2][r] * s0;
                const float o1 = acc[mt][1][r] * c1 + acc[mt][3][r] * s1;
                const float o2 = acc[mt][2][r] * c0 - acc[mt][0][r] * s0;
                const float o3 = acc[mt][3][r] * c1 - acc[mt][1][r] * s1;
                Cp[0]  = f2bf(o0 * rinv);
                Cp[16] = f2bf(o1 * rinv);
                Cp[32] = f2bf(o2 * rinv);
                Cp[48] = f2bf(o3 * rinv);
            } else {
#pragma unroll
                for (int nt = 0; nt < 4; ++nt) Cp[nt * 16] = f2bf(acc[mt][nt][r]);
            }
        }
}

// ---------------------------------------------------------------------------
// bf16 MFMA flash attention, fixed-max softmax (scores provably in [-8,8]
// after rmsnorm), fold-paired q-tiles (qp, 31-qp) for uniform block cost and
// K/V staging reuse. No running max / alpha rescale; row-sum reduced once.
// ---------------------------------------------------------------------------
__global__ __launch_bounds__(256, 4) void attn_mfma(const ushort_t* __restrict__ qkv,
                                                    ushort_t* __restrict__ y) {
    const int qp = blockIdx.x;   // 0..15
    const int h  = blockIdx.y;   // 0..15
    const int b  = blockIdx.z;   // 0..3
    const int tid  = threadIdx.x;
    const int w    = tid >> 6;
    const int lane = tid & 63;
    const int quad = lane >> 4;
    const int lm   = lane & 15;
    const int qtA = qp, qtB = 31 - qp;

    __shared__ ushort_t Ks[64][72];    // K[n][d]
    __shared__ ushort_t Vt[64][72];    // V^T[d][n]
    __shared__ ushort_t Ps[4][16][72]; // per-wave P[m][n]

    short8 qfA[2], qfB[2];
    {
        const ushort_t* qa = qkv + (size_t)(b * TT + qtA * 64 + w * 16 + lm) * (3 * CC) + h * DD;
        const ushort_t* qb = qkv + (size_t)(b * TT + qtB * 64 + w * 16 + lm) * (3 * CC) + h * DD;
        qfA[0] = *(const short8*)(qa + quad * 8);
        qfA[1] = *(const short8*)(qa + 32 + quad * 8);
        qfB[0] = *(const short8*)(qb + quad * 8);
        qfB[1] = *(const short8*)(qb + 32 + quad * 8);
    }

    f32x4 OA[4], OB[4];
#pragma unroll
    for (int dt = 0; dt < 4; ++dt) {
        OA[dt] = (f32x4){0.f, 0.f, 0.f, 0.f};
        OB[dt] = (f32x4){0.f, 0.f, 0.f, 0.f};
    }
    float psA[4] = {0.f, 0.f, 0.f, 0.f};
    float psB[4] = {0.f, 0.f, 0.f, 0.f};

    const int sn = tid >> 2;
    const int sd = (tid & 3) * 16;

    // process one staged 64-key tile against one q-tile's fragments
    auto process = [&](short8 (&qf)[2], f32x4 (&O)[4], float (&ps)[4], bool diag) {
        f32x4 sf[4];
#pragma unroll
        for (int nt = 0; nt < 4; ++nt) sf[nt] = (f32x4){0.f, 0.f, 0.f, 0.f};
#pragma unroll
        for (int kk = 0; kk < 2; ++kk)
#pragma unroll
            for (int nt = 0; nt < 4; ++nt) {
                short8 kf = *(const short8*)&Ks[nt * 16 + lm][kk * 32 + quad * 8];
                sf[nt] = __builtin_amdgcn_mfma_f32_16x16x32_bf16(qf[kk], kf, sf[nt], 0, 0, 0);
            }
        // p = exp(s*0.125 - 8); provably <= e^0.1. No max tracking needed.
#pragma unroll
        for (int r = 0; r < 4; ++r) {
            const int rloc = w * 16 + quad * 4 + r;   // row within q-tile
#pragma unroll
            for (int nt = 0; nt < 4; ++nt) {
                float s = sf[nt][r] * 0.125f - 8.f;
                if (diag) s = (nt * 16 + lm <= rloc) ? s : -1e30f;
                const float p = __expf(s);
                ps[r] += p;
                Ps[w][quad * 4 + r][nt * 16 + lm] = f2bf(p);
            }
        }
#pragma unroll
        for (int kk = 0; kk < 2; ++kk) {
            short8 pf = *(const short8*)&Ps[w][lm][kk * 32 + quad * 8];
#pragma unroll
            for (int dt = 0; dt < 4; ++dt) {
                short8 vf = *(const short8*)&Vt[dt * 16 + lm][kk * 32 + quad * 8];
                O[dt] = __builtin_amdgcn_mfma_f32_16x16x32_bf16(pf, vf, O[dt], 0, 0, 0);
            }
        }
    };

    for (int kt = 0; kt <= qtB; ++kt) {
        __syncthreads();
        {
            const ushort_t* kp = qkv + (size_t)(b * TT + kt * 64 + sn) * (3 * CC) + CC + h * DD + sd;
            short8 k0v = *(const short8*)kp;
            short8 k1v = *(const short8*)(kp + 8);
            short8 v0v = *(const short8*)(kp + CC);
            short8 v1v = *(const short8*)(kp + CC + 8);
            *(short8*)&Ks[sn][sd]     = k0v;
            *(short8*)&Ks[sn][sd + 8] = k1v;
#pragma unroll
            for (int jj = 0; jj < 8; ++jj) {
                Vt[sd + jj][sn]     = (ushort_t)v0v[jj];
                Vt[sd + 8 + jj][sn] = (ushort_t)v1v[jj];
            }
        }
        __syncthreads();

        if (kt <= qtA) process(qfA, OA, psA, kt == qtA);
        process(qfB, OB, psB, kt == qtB);
    }

    // epilogue: reduce row sums once, scale, store
    auto epi = [&](f32x4 (&O)[4], float (&ps)[4], int qt) {
#pragma unroll
        for (int r = 0; r < 4; ++r) {
            float l = ps[r];
            l += __shfl_xor(l, 1);
            l += __shfl_xor(l, 2);
            l += __shfl_xor(l, 4);
            l += __shfl_xor(l, 8);
            const float inv_l = 1.f / l;
            ushort_t* yp = y + (size_t)(b * TT + qt * 64 + w * 16 + quad * 4 + r) * CC + h * DD + lm;
#pragma unroll
            for (int dt = 0; dt < 4; ++dt) yp[dt * 16] = f2bf(O[dt][r] * inv_l);
        }
    };
    epi(OA, psA, qtA);
    epi(OB, psB, qtB);
}

// ---------------------------------------------------------------------------
extern "C" void kernel_launch(void* const* d_in, const int* in_sizes, int n_in,
                              void* d_out, int out_size, void* d_ws, size_t ws_size,
                              hipStream_t stream) {
    const float* x      = (const float*)d_in[0];   // (4,2048,1024)
    const float* cosb   = (const float*)d_in[1];   // (1,2048,1,32)
    const float* sinb   = (const float*)d_in[2];
    const float* w_attn = (const float*)d_in[3];   // (3072,1024)
    const float* w_proj = (const float*)d_in[4];   // (1024,1024)
    float* out = (float*)d_out;                    // (4,2048,1024)

    // workspace layout (bf16 elements)
    ushort_t* qkvb = (ushort_t*)d_ws;                       // 8192*3072
    ushort_t* yb   = qkvb + (size_t)8192 * 3072;            // 8192*1024
    ushort_t* xb   = yb   + (size_t)8192 * 1024;            // 8192*1024
    ushort_t* wab  = xb   + (size_t)8192 * 1024;            // 3072*1024
    ushort_t* wpb  = wab  + (size_t)3072 * 1024;            // 1024*1024

    cast_bf16<<<(8192 * 1024 / 8 + 255) / 256, 256, 0, stream>>>(x, xb, 8192 * 1024 / 8);
    cast_bf16<<<(3072 * 1024 / 8 + 255) / 256, 256, 0, stream>>>(w_attn, wab, 3072 * 1024 / 8);
    cast_bf16<<<(1024 * 1024 / 8 + 255) / 256, 256, 0, stream>>>(w_proj, wpb, 1024 * 1024 / 8);

    // qkv = x @ w_attn^T with fused rope+rmsnorm on q,k
    gemm_qkv<<<dim3(3072 / 128, 8192 / 128), 256, 0, stream>>>(
        xb, wab, qkvb, cosb, sinb, 8192, 3072, 1024);

    // causal attention -> yb
    attn_mfma<<<dim3(16, HH, 4), 256, 0, stream>>>(qkvb, yb);

    // out = y @ w_proj^T (fp32 out)
    gemm_bt<true><<<dim3(1024 / 128, 8192 / 128), 256, 0, stream>>>(
        yb, wpb, out, 8192, 1024, 1024);
}